// Round 12
// baseline (1222.663 us; speedup 1.0000x reference)
//
#include <hip/hip_runtime.h>

#define NB_ 5      // N_BASIS
#define MD_ 5      // MAX_DELAY
#define CSL 128    // pre-neurons per coarse bucket (power of 2)
#define CAP 6144   // records per bucket (avg 5120 at E=2M,N=50k; +14 sigma)
#define CH  4096   // edges per partition block
#define RING 6     // i_rec ring slots (current + 5 future)

// ---------------------------------------------------------------------------
// Build: edges sorted by PRE neuron (outgoing CSR), 4-byte records.
//   record u32 = localn(7) << 24 | d(3) << 21 | eid(21)
//   rp[n] = {start, end} absolute indices into edgeRec (bucket-padded layout)
// ---------------------------------------------------------------------------

__global__ __launch_bounds__(256) void init_kernel(
    const float* __restrict__ decay, const float* __restrict__ cf,
    const float* __restrict__ g,     const float* __restrict__ vth,
    const float* __restrict__ vrst,  const float* __restrict__ nrm,
    const float* __restrict__ tref,  const float* __restrict__ ek,
    const float* __restrict__ am,
    float4* __restrict__ pk, float* __restrict__ v, int N)
{
    int n = blockIdx.x * blockDim.x + threadIdx.x;
    if (n >= N) return;
    pk[3 * n]     = make_float4(decay[n], cf[n], g[n], vth[n]);
    pk[3 * n + 1] = make_float4(vrst[n], nrm[n], tref[n], ek[2 * n]);
    pk[3 * n + 2] = make_float4(ek[2 * n + 1], am[2 * n], am[2 * n + 1], 0.0f);
    v[n] = vrst[n];
}

__global__ __launch_bounds__(256) void partition_kernel(
    const int* __restrict__ pre_idx,
    int* __restrict__ gcur,          // NC cursors (zeroed)
    unsigned* __restrict__ part,     // NC*CAP
    int E, int N)
{
    __shared__ int cntL[512];        // NC = 391 <= 512
    __shared__ int posL[512];
    int t = threadIdx.x;
    cntL[t] = 0; cntL[t + 256] = 0;
    __syncthreads();
    int e0 = blockIdx.x * CH;
    int e1 = min(e0 + CH, E);
    for (int e = e0 + t; e < e1; e += 256) {
        int pre = pre_idx[e];
        int d = pre / N;
        int n = pre - d * N;
        atomicAdd(&cntL[n >> 7], 1);
    }
    __syncthreads();
    for (int b = t; b < 512; b += 256)
        posL[b] = cntL[b] ? atomicAdd(&gcur[b], cntL[b]) : 0;
    __syncthreads();
    for (int e = e0 + t; e < e1; e += 256) {
        int pre = pre_idx[e];
        int d = pre / N;
        int n = pre - d * N;
        int b = n >> 7;
        int p = atomicAdd(&posL[b], 1);
        if (p < CAP)   // never triggers for uniform pre_idx (+14 sigma margin)
            part[(size_t)b * CAP + p] =
                ((unsigned)(n & (CSL - 1)) << 24) | ((unsigned)d << 21) | (unsigned)e;
    }
}

// one block per coarse bucket: LDS counting sort over CSL local pre-neurons
__global__ __launch_bounds__(256) void bucket_sort_kernel(
    const int* __restrict__ gcur,
    const unsigned* __restrict__ part,
    unsigned* __restrict__ edgeRec,   // NC*CAP
    uint2* __restrict__ rp,           // per-neuron {start,end}
    int N)
{
    __shared__ int h[CSL];
    __shared__ int sc_[CSL];
    __shared__ int pos_[CSL];
    int c = blockIdx.x, t = threadIdx.x;
    int cnt = min(gcur[c], CAP);
    size_t base = (size_t)c * CAP;
    if (t < CSL) h[t] = 0;
    __syncthreads();
    for (int i = t; i < cnt; i += 256)
        atomicAdd(&h[part[base + i] >> 24], 1);
    __syncthreads();
    if (t < CSL) sc_[t] = h[t];
    __syncthreads();
    for (int off = 1; off < CSL; off <<= 1) {
        int y = 0;
        if (t < CSL && t >= off) y = sc_[t - off];
        __syncthreads();
        if (t < CSL && t >= off) sc_[t] += y;
        __syncthreads();
    }
    if (t < CSL) {
        int end = sc_[t];                 // inclusive end (local)
        pos_[t] = (int)base + end - h[t]; // exclusive start (absolute)
        int gn = c * CSL + t;
        if (gn < N)
            rp[gn] = make_uint2((unsigned)(base + end - h[t]),
                                (unsigned)(base + end));
    }
    __syncthreads();
    for (int i = t; i < cnt; i += 256) {
        unsigned q = part[base + i];
        int dst = atomicAdd(&pos_[q >> 24], 1);
        edgeRec[dst] = q;
    }
}

// ---------------------------------------------------------------------------
// Per-step kernel: neuron update + immediate push of outgoing spikes into
// future i_rec ring slots. ONE dispatch per step; no edge kernel, no bits.
// ---------------------------------------------------------------------------

__global__ __launch_bounds__(256) void step_kernel(
    const float* __restrict__ x_t,        // ext_input + t*n5
    float*       __restrict__ psc,        // n5
    const float* __restrict__ sd,         // syn_decay
    const float* __restrict__ pi,         // psc_initial
    const float4* __restrict__ pk,        // {decay,cf,g,vth}{vrst,nrm,tref,ek0}{ek1,am0,am1,_}
    float* __restrict__ v,
    float* __restrict__ r,
    float* __restrict__ asc,              // (N,2)
    float* __restrict__ ring,             // RING*n5 i_rec accumulators
    const int* __restrict__ scnt,         // scnt[MD+u] = spike count of step u
    int*       __restrict__ scnt_new,     // &scnt[MD+t]
    const float* __restrict__ out_prev,   // out + (t-1)*N (t>=1)
    float*       __restrict__ out_t,      // out + t*N
    const uint2*    __restrict__ rp,      // outgoing CSR {start,end}
    const unsigned* __restrict__ edgeRec,
    const float*    __restrict__ weights,
    const float*    __restrict__ edge_basis,
    const int*      __restrict__ post_idx,
    int t, int n5, int N)
{
    int n = blockIdx.x * blockDim.x + threadIdx.x;
    bool has = (n < N);

    // spike count in window t-5..t-1 (scnt offset by MD, head zeroed)
    const int* sw = scnt + t;
    int scw = sw[0] + sw[1] + sw[2] + sw[3] + sw[4];

    float z = 0.0f;
    if (has) {
        // ---- read & clear this step's i_rec ring slot (skip when quiet) ----
        float ir0 = 0.f, ir1 = 0.f, ir2 = 0.f, ir3 = 0.f, ir4 = 0.f;
        float* rg = ring + (size_t)(t % RING) * n5 + (size_t)n * NB_;
        if (scw > 0) {
            ir0 = rg[0]; ir1 = rg[1]; ir2 = rg[2]; ir3 = rg[3]; ir4 = rg[4];
            rg[0] = 0.f; rg[1] = 0.f; rg[2] = 0.f; rg[3] = 0.f; rg[4] = 0.f;
        }

        // ---- psc recurrence + input current (k ascending, ref order) -------
        const float* xp  = x_t + (size_t)n * NB_;
        float*       pp  = psc + (size_t)n * NB_;
        const float* sdp = sd  + (size_t)n * NB_;
        const float* pip = pi  + (size_t)n * NB_;
        float ic = 0.0f, pv;
        pv = pp[0] * sdp[0] + (ir0 + xp[0]) * pip[0]; pp[0] = pv; ic += pv;
        pv = pp[1] * sdp[1] + (ir1 + xp[1]) * pip[1]; pp[1] = pv; ic += pv;
        pv = pp[2] * sdp[2] + (ir2 + xp[2]) * pip[2]; pp[2] = pv; ic += pv;
        pv = pp[3] * sdp[3] + (ir3 + xp[3]) * pip[3]; pp[3] = pv; ic += pv;
        pv = pp[4] * sdp[4] + (ir4 + xp[4]) * pip[4]; pp[4] = pv; ic += pv;

        float4 P0 = pk[3 * n], P1 = pk[3 * n + 1], P2 = pk[3 * n + 2];

        float pz = (t > 0) ? out_prev[n] : 0.0f;

        float a0 = P1.w * asc[2 * n]     + pz * P2.y;
        float a1 = P2.x * asc[2 * n + 1] + pz * P2.z;
        asc[2 * n]     = a0;
        asc[2 * n + 1] = a1;

        float c1 = ic + (a0 + a1) + P0.z;
        float nv = P0.x * v[n] + P0.y * c1;
        if (pz > 0.5f) nv = P1.x;

        float vsc = (nv - P0.w) / P1.y;
        z = (vsc > 0.0f) ? 1.0f : 0.0f;
        float rr = r[n];
        if (rr > 0.0f) z = 0.0f;

        r[n] = fmaxf(rr + z * P1.z - 1.0f, 0.0f);   // DT = 1.0
        v[n] = nv;
        out_t[n] = z;

        // ---- push outgoing edges into future ring slots (firing lanes only)
        if (z != 0.0f) {
            uint2 row = rp[n];
            for (unsigned i = row.x; i < row.y; ++i) {
                unsigned q = edgeRec[i];
                int d = (int)((q >> 21) & 7u);
                int e = (int)(q & 0x1FFFFFu);
                float w = weights[e];
                const float* bs = edge_basis + (size_t)e * NB_;
                float* dst = ring + (size_t)((t + 1 + d) % RING) * n5
                           + (size_t)post_idx[e] * NB_;
                atomicAdd(dst + 0, w * bs[0]);
                atomicAdd(dst + 1, w * bs[1]);
                atomicAdd(dst + 2, w * bs[2]);
                atomicAdd(dst + 3, w * bs[3]);
                atomicAdd(dst + 4, w * bs[4]);
            }
        }
    }

    // per-step spike count (one atomic per spiking wave)
    unsigned long long m = __ballot(z != 0.0f);
    if ((threadIdx.x & 63) == 0 && m)
        atomicAdd(scnt_new, (int)__popcll(m));
}

// ---------------------------------------------------------------------------
// Launcher
// ---------------------------------------------------------------------------

extern "C" void kernel_launch(void* const* d_in, const int* in_sizes, int n_in,
                              void* d_out, int out_size, void* d_ws, size_t ws_size,
                              hipStream_t stream)
{
    const float* weights        = (const float*)d_in[0];
    const float* edge_basis     = (const float*)d_in[1];
    const float* ext_input      = (const float*)d_in[2];
    const float* decay          = (const float*)d_in[3];
    const float* current_factor = (const float*)d_in[4];
    const float* gathered_g     = (const float*)d_in[5];
    const float* v_th           = (const float*)d_in[6];
    const float* v_reset        = (const float*)d_in[7];
    const float* normalizer     = (const float*)d_in[8];
    const float* t_ref          = (const float*)d_in[9];
    const float* exp_dt_k       = (const float*)d_in[10];
    const float* asc_amps       = (const float*)d_in[11];
    const float* syn_decay      = (const float*)d_in[12];
    const float* psc_initial    = (const float*)d_in[13];
    const int*   pre_idx        = (const int*)d_in[14];
    const int*   post_idx       = (const int*)d_in[15];

    const int E  = in_sizes[0];
    const int N  = in_sizes[3];
    const int n5 = N * NB_;
    const int T  = in_sizes[2] / n5;            // B = 1

    const int NC = (N + CSL - 1) / CSL;         // 391

    float* out = (float*)d_out;

    // ---- workspace layout ---------------------------------------------------
    char* wsb = (char*)d_ws;
    size_t o = 0;
    // zero group (one memset):
    int*   gcur = (int*)(wsb + o);   o += 512 * 4;
    int*   scnt = (int*)(wsb + o);   o += (size_t)(T + MD_) * 4;
    o = (o + 15) & ~(size_t)15;
    float* psc  = (float*)(wsb + o); o += (size_t)n5 * 4;
    float* r    = (float*)(wsb + o); o += (size_t)N * 4;
    float* asc  = (float*)(wsb + o); o += (size_t)2 * N * 4;
    o = (o + 15) & ~(size_t)15;
    float* ring = (float*)(wsb + o); o += (size_t)RING * n5 * 4;
    size_t zero_bytes = o;                      // ~7.9 MB
    // non-zeroed:
    float*  v       = (float*)(wsb + o);  o += (size_t)N * 4;
    float4* pk      = (float4*)(wsb + o); o += (size_t)N * 12 * 4;
    uint2*  rp      = (uint2*)(wsb + o);  o += (size_t)N * 8;
    o = (o + 15) & ~(size_t)15;
    unsigned* part    = (unsigned*)(wsb + o); o += (size_t)NC * CAP * 4;
    unsigned* edgeRec = (unsigned*)(wsb + o); o += (size_t)NC * CAP * 4;

    // ---- build (every launch; graph replays everything) --------------------
    hipMemsetAsync(d_ws, 0, zero_bytes, stream);

    init_kernel<<<(N + 255) / 256, 256, 0, stream>>>(
        decay, current_factor, gathered_g, v_th, v_reset, normalizer, t_ref,
        exp_dt_k, asc_amps, pk, v, N);

    const int nbe = (E + CH - 1) / CH;   // 489
    partition_kernel<<<nbe, 256, 0, stream>>>(pre_idx, gcur, part, E, N);
    bucket_sort_kernel<<<NC, 256, 0, stream>>>(gcur, part, edgeRec, rp, N);

    // ---- time loop: ONE kernel per step -------------------------------------
    const int nblk = (N + 255) / 256;    // 196
    for (int t = 0; t < T; ++t) {
        step_kernel<<<nblk, 256, 0, stream>>>(
            ext_input + (size_t)t * n5,
            psc, syn_decay, psc_initial,
            pk, v, r, asc,
            ring, scnt, scnt + MD_ + t,
            out + (size_t)(t > 0 ? t - 1 : 0) * N,
            out + (size_t)t * N,
            rp, edgeRec, weights, edge_basis, post_idx,
            t, n5, N);
    }
}

// Round 13
// 270.378 us; speedup vs baseline: 4.5220x; 4.5220x over previous
//
#include <hip/hip_runtime.h>

#define NB_ 5      // N_BASIS
#define MD_ 5      // MAX_DELAY
#define CSL 128    // pre-neurons per coarse bucket (power of 2)
#define CAP 6144   // records per bucket (avg 5120 at E=2M,N=50k; +14 sigma)
#define CH  4096   // edges per partition block
#define RING 6     // i_rec ring slots (current + 5 future)

// ---------------------------------------------------------------------------
// Build: edges sorted by PRE neuron (outgoing CSR), 4-byte records.
//   record u32 = localn(7) << 24 | d(3) << 21 | eid(21)     (E=2M < 2^21)
//   rp[n] = {start, end} absolute indices into edgeRec (bucket-padded layout)
// ---------------------------------------------------------------------------

__global__ __launch_bounds__(256) void init_kernel(
    const float* __restrict__ decay, const float* __restrict__ cf,
    const float* __restrict__ g,     const float* __restrict__ vth,
    const float* __restrict__ vrst,  const float* __restrict__ nrm,
    const float* __restrict__ tref,  const float* __restrict__ ek,
    const float* __restrict__ am,
    float4* __restrict__ pk, float* __restrict__ v, int N)
{
    int n = blockIdx.x * blockDim.x + threadIdx.x;
    if (n >= N) return;
    pk[3 * n]     = make_float4(decay[n], cf[n], g[n], vth[n]);
    pk[3 * n + 1] = make_float4(vrst[n], nrm[n], tref[n], ek[2 * n]);
    pk[3 * n + 2] = make_float4(ek[2 * n + 1], am[2 * n], am[2 * n + 1], 0.0f);
    v[n] = vrst[n];
}

__global__ __launch_bounds__(256) void partition_kernel(
    const int* __restrict__ pre_idx,
    int* __restrict__ gcur,          // NC cursors (zeroed)
    unsigned* __restrict__ part,     // NC*CAP
    int E, int N)
{
    __shared__ int cntL[512];        // NC = 391 <= 512
    __shared__ int posL[512];
    int t = threadIdx.x;
    cntL[t] = 0; cntL[t + 256] = 0;
    __syncthreads();
    int e0 = blockIdx.x * CH;
    int e1 = min(e0 + CH, E);
    for (int e = e0 + t; e < e1; e += 256) {
        int pre = pre_idx[e];
        int d = pre / N;
        int n = pre - d * N;
        atomicAdd(&cntL[n >> 7], 1);
    }
    __syncthreads();
    for (int b = t; b < 512; b += 256)
        posL[b] = cntL[b] ? atomicAdd(&gcur[b], cntL[b]) : 0;
    __syncthreads();
    for (int e = e0 + t; e < e1; e += 256) {
        int pre = pre_idx[e];
        int d = pre / N;
        int n = pre - d * N;
        int b = n >> 7;
        int p = atomicAdd(&posL[b], 1);
        if (p < CAP)   // never triggers for uniform pre_idx (+14 sigma margin)
            part[(size_t)b * CAP + p] =
                ((unsigned)(n & (CSL - 1)) << 24) | ((unsigned)d << 21) | (unsigned)e;
    }
}

// one block per coarse bucket: LDS counting sort over CSL local pre-neurons
__global__ __launch_bounds__(256) void bucket_sort_kernel(
    const int* __restrict__ gcur,
    const unsigned* __restrict__ part,
    unsigned* __restrict__ edgeRec,   // NC*CAP
    uint2* __restrict__ rp,           // per-neuron {start,end}
    int N)
{
    __shared__ int h[CSL];
    __shared__ int sc_[CSL];
    __shared__ int pos_[CSL];
    int c = blockIdx.x, t = threadIdx.x;
    int cnt = min(gcur[c], CAP);
    size_t base = (size_t)c * CAP;
    if (t < CSL) h[t] = 0;
    __syncthreads();
    for (int i = t; i < cnt; i += 256)
        atomicAdd(&h[part[base + i] >> 24], 1);
    __syncthreads();
    if (t < CSL) sc_[t] = h[t];
    __syncthreads();
    for (int off = 1; off < CSL; off <<= 1) {
        int y = 0;
        if (t < CSL && t >= off) y = sc_[t - off];
        __syncthreads();
        if (t < CSL && t >= off) sc_[t] += y;
        __syncthreads();
    }
    if (t < CSL) {
        int end = sc_[t];                 // inclusive end (local)
        pos_[t] = (int)base + end - h[t]; // exclusive start (absolute)
        int gn = c * CSL + t;
        if (gn < N)
            rp[gn] = make_uint2((unsigned)(base + end - h[t]),
                                (unsigned)(base + end));
    }
    __syncthreads();
    for (int i = t; i < cnt; i += 256) {
        unsigned q = part[base + i];
        int dst = atomicAdd(&pos_[q >> 24], 1);
        edgeRec[dst] = q;
    }
}

// ---------------------------------------------------------------------------
// Per-step kernel: neuron update + BLOCK-COOPERATIVE push of firing neurons'
// outgoing edges into future i_rec ring slots. One dispatch per step.
// ---------------------------------------------------------------------------

__global__ __launch_bounds__(256) void step_kernel(
    const float* __restrict__ x_t,        // ext_input + t*n5
    float*       __restrict__ psc,        // n5
    const float* __restrict__ sd,         // syn_decay
    const float* __restrict__ pi,         // psc_initial
    const float4* __restrict__ pk,        // {decay,cf,g,vth}{vrst,nrm,tref,ek0}{ek1,am0,am1,_}
    float* __restrict__ v,
    float* __restrict__ r,
    float* __restrict__ asc,              // (N,2)
    float* __restrict__ ring,             // RING*n5 i_rec accumulators
    const int* __restrict__ scnt,         // scnt[MD+u] = spike count of step u
    int*       __restrict__ scnt_new,     // &scnt[MD+t]
    const float* __restrict__ out_prev,   // out + (t-1)*N (t>=1)
    float*       __restrict__ out_t,      // out + t*N
    const uint2*    __restrict__ rp,      // outgoing CSR {start,end}
    const unsigned* __restrict__ edgeRec,
    const float*    __restrict__ weights,
    const float*    __restrict__ edge_basis,
    const int*      __restrict__ post_idx,
    int t, int n5, int N)
{
    __shared__ int   nf_s;
    __shared__ uint2 rowsL[256];
    __shared__ int   scL[256];
    __shared__ int   pref[257];

    const int tloc = threadIdx.x;
    const int n = blockIdx.x * blockDim.x + tloc;
    const bool has = (n < N);
    if (tloc == 0) nf_s = 0;
    __syncthreads();

    // spike count in window t-5..t-1 (scnt offset by MD, head zeroed)
    const int* sw = scnt + t;
    int scw = sw[0] + sw[1] + sw[2] + sw[3] + sw[4];

    float z = 0.0f;
    if (has) {
        // ---- read & clear this step's i_rec ring slot (skip when quiet) ----
        float ir0 = 0.f, ir1 = 0.f, ir2 = 0.f, ir3 = 0.f, ir4 = 0.f;
        float* rg = ring + (size_t)(t % RING) * n5 + (size_t)n * NB_;
        if (scw > 0) {
            ir0 = rg[0]; ir1 = rg[1]; ir2 = rg[2]; ir3 = rg[3]; ir4 = rg[4];
            rg[0] = 0.f; rg[1] = 0.f; rg[2] = 0.f; rg[3] = 0.f; rg[4] = 0.f;
        }

        // ---- psc recurrence + input current (k ascending, ref order) -------
        const float* xp  = x_t + (size_t)n * NB_;
        float*       pp  = psc + (size_t)n * NB_;
        const float* sdp = sd  + (size_t)n * NB_;
        const float* pip = pi  + (size_t)n * NB_;
        float ic = 0.0f, pv;
        pv = pp[0] * sdp[0] + (ir0 + xp[0]) * pip[0]; pp[0] = pv; ic += pv;
        pv = pp[1] * sdp[1] + (ir1 + xp[1]) * pip[1]; pp[1] = pv; ic += pv;
        pv = pp[2] * sdp[2] + (ir2 + xp[2]) * pip[2]; pp[2] = pv; ic += pv;
        pv = pp[3] * sdp[3] + (ir3 + xp[3]) * pip[3]; pp[3] = pv; ic += pv;
        pv = pp[4] * sdp[4] + (ir4 + xp[4]) * pip[4]; pp[4] = pv; ic += pv;

        float4 P0 = pk[3 * n], P1 = pk[3 * n + 1], P2 = pk[3 * n + 2];

        float pz = (t > 0) ? out_prev[n] : 0.0f;

        float a0 = P1.w * asc[2 * n]     + pz * P2.y;
        float a1 = P2.x * asc[2 * n + 1] + pz * P2.z;
        asc[2 * n]     = a0;
        asc[2 * n + 1] = a1;

        float c1 = ic + (a0 + a1) + P0.z;
        float nv = P0.x * v[n] + P0.y * c1;
        if (pz > 0.5f) nv = P1.x;

        float vsc = (nv - P0.w) / P1.y;
        z = (vsc > 0.0f) ? 1.0f : 0.0f;
        float rr = r[n];
        if (rr > 0.0f) z = 0.0f;

        r[n] = fmaxf(rr + z * P1.z - 1.0f, 0.0f);   // DT = 1.0
        v[n] = nv;
        out_t[n] = z;

        // enqueue this neuron's outgoing row for the cooperative push
        if (z != 0.0f) {
            int idx = atomicAdd(&nf_s, 1);
            rowsL[idx] = rp[n];
        }
    }

    // per-step spike count (one atomic per spiking wave)
    unsigned long long m = __ballot(z != 0.0f);
    if ((tloc & 63) == 0 && m)
        atomicAdd(scnt_new, (int)__popcll(m));

    __syncthreads();
    int nf = nf_s;                 // uniform across block
    if (nf == 0) return;

    // ---- prefix-sum of firing rows' edge counts -----------------------------
    int cnt = (tloc < nf) ? (int)(rowsL[tloc].y - rowsL[tloc].x) : 0;
    scL[tloc] = cnt;
    __syncthreads();
    int x = cnt;
    for (int off = 1; off < 256; off <<= 1) {
        int y = (tloc >= off) ? scL[tloc - off] : 0;
        __syncthreads();
        x += y;
        scL[tloc] = x;
        __syncthreads();
    }
    pref[tloc + 1] = scL[tloc];
    if (tloc == 0) pref[0] = 0;
    __syncthreads();

    // ---- all 256 threads process the union of firing edges ------------------
    int tot = pref[nf];
    for (int j = tloc; j < tot; j += 256) {
        int lo = 0, hi = nf - 1;                 // largest row with pref[row] <= j
        while (lo < hi) {
            int mid = (lo + hi + 1) >> 1;
            if (pref[mid] <= j) lo = mid; else hi = mid - 1;
        }
        int i = (int)rowsL[lo].x + (j - pref[lo]);
        unsigned q = edgeRec[i];
        int d = (int)((q >> 21) & 7u);
        int e = (int)(q & 0x1FFFFFu);
        float w = weights[e];
        const float* bs = edge_basis + (size_t)e * NB_;
        float* dst = ring + (size_t)((t + 1 + d) % RING) * n5
                   + (size_t)post_idx[e] * NB_;
        atomicAdd(dst + 0, w * bs[0]);
        atomicAdd(dst + 1, w * bs[1]);
        atomicAdd(dst + 2, w * bs[2]);
        atomicAdd(dst + 3, w * bs[3]);
        atomicAdd(dst + 4, w * bs[4]);
    }
}

// ---------------------------------------------------------------------------
// Launcher
// ---------------------------------------------------------------------------

extern "C" void kernel_launch(void* const* d_in, const int* in_sizes, int n_in,
                              void* d_out, int out_size, void* d_ws, size_t ws_size,
                              hipStream_t stream)
{
    const float* weights        = (const float*)d_in[0];
    const float* edge_basis     = (const float*)d_in[1];
    const float* ext_input      = (const float*)d_in[2];
    const float* decay          = (const float*)d_in[3];
    const float* current_factor = (const float*)d_in[4];
    const float* gathered_g     = (const float*)d_in[5];
    const float* v_th           = (const float*)d_in[6];
    const float* v_reset        = (const float*)d_in[7];
    const float* normalizer     = (const float*)d_in[8];
    const float* t_ref          = (const float*)d_in[9];
    const float* exp_dt_k       = (const float*)d_in[10];
    const float* asc_amps       = (const float*)d_in[11];
    const float* syn_decay      = (const float*)d_in[12];
    const float* psc_initial    = (const float*)d_in[13];
    const int*   pre_idx        = (const int*)d_in[14];
    const int*   post_idx       = (const int*)d_in[15];

    const int E  = in_sizes[0];
    const int N  = in_sizes[3];
    const int n5 = N * NB_;
    const int T  = in_sizes[2] / n5;            // B = 1

    const int NC = (N + CSL - 1) / CSL;         // 391

    float* out = (float*)d_out;

    // ---- workspace layout ---------------------------------------------------
    char* wsb = (char*)d_ws;
    size_t o = 0;
    // zero group (one memset):
    int*   gcur = (int*)(wsb + o);   o += 512 * 4;
    int*   scnt = (int*)(wsb + o);   o += (size_t)(T + MD_) * 4;
    o = (o + 15) & ~(size_t)15;
    float* psc  = (float*)(wsb + o); o += (size_t)n5 * 4;
    float* r    = (float*)(wsb + o); o += (size_t)N * 4;
    float* asc  = (float*)(wsb + o); o += (size_t)2 * N * 4;
    o = (o + 15) & ~(size_t)15;
    float* ring = (float*)(wsb + o); o += (size_t)RING * n5 * 4;
    size_t zero_bytes = o;                      // ~7.9 MB
    // non-zeroed:
    float*  v       = (float*)(wsb + o);  o += (size_t)N * 4;
    float4* pk      = (float4*)(wsb + o); o += (size_t)N * 12 * 4;
    uint2*  rp      = (uint2*)(wsb + o);  o += (size_t)N * 8;
    o = (o + 15) & ~(size_t)15;
    unsigned* part    = (unsigned*)(wsb + o); o += (size_t)NC * CAP * 4;
    unsigned* edgeRec = (unsigned*)(wsb + o); o += (size_t)NC * CAP * 4;

    // ---- build (every launch; graph replays everything) --------------------
    hipMemsetAsync(d_ws, 0, zero_bytes, stream);

    init_kernel<<<(N + 255) / 256, 256, 0, stream>>>(
        decay, current_factor, gathered_g, v_th, v_reset, normalizer, t_ref,
        exp_dt_k, asc_amps, pk, v, N);

    const int nbe = (E + CH - 1) / CH;   // 489
    partition_kernel<<<nbe, 256, 0, stream>>>(pre_idx, gcur, part, E, N);
    bucket_sort_kernel<<<NC, 256, 0, stream>>>(gcur, part, edgeRec, rp, N);

    // ---- time loop: ONE kernel per step -------------------------------------
    const int nblk = (N + 255) / 256;    // 196
    for (int t = 0; t < T; ++t) {
        step_kernel<<<nblk, 256, 0, stream>>>(
            ext_input + (size_t)t * n5,
            psc, syn_decay, psc_initial,
            pk, v, r, asc,
            ring, scnt, scnt + MD_ + t,
            out + (size_t)(t > 0 ? t - 1 : 0) * N,
            out + (size_t)t * N,
            rp, edgeRec, weights, edge_basis, post_idx,
            t, n5, N);
    }
}